// Round 1
// baseline (640.206 us; speedup 1.0000x reference)
//
#include <hip/hip_runtime.h>
#include <math.h>

// VectorQuantizer: z [8,256,32,32] f32, codebook [8192,256] f32
// outputs (flat f32): z_q [2097152] NCHW, idx [8192] (as float), loss, perplexity
#define KC 8192      // num codes
#define DD 256       // latent dim
#define NP 8192      // 8*32*32 points
#define KSPLIT 8
#define ZQ_ELEMS 2097152

// ws layout (bytes)
#define OFF_W     0u          // f32 [8192*256] normalized codebook
#define OFF_WSQ   8388608u    // f32 [8192]
#define OFF_ZSQ   8421376u    // f32 [8192]
#define OFF_PVAL  8454144u    // f32 [8*8192]
#define OFF_PIDX  8716288u    // i32 [8*8192]
#define OFF_IDX   8978432u    // i32 [8192]
#define OFF_HIST  9011200u    // i32 [8192]
#define OFF_LOSS  9043968u    // f64 [1]
// memset region: OFF_HIST .. OFF_LOSS+8  (32776 bytes)

__device__ inline double waveReduceD(double v) {
#pragma unroll
    for (int off = 32; off; off >>= 1) v += __shfl_down(v, off, 64);
    return v;
}

// one block per code row: normalize, write w and wsq
__global__ __launch_bounds__(256) void normalize_kernel(
    const float* __restrict__ cb, float* __restrict__ w, float* __restrict__ wsq) {
    __shared__ double lred[4];
    __shared__ float mh;
    int k = blockIdx.x, t = threadIdx.x;
    float c = cb[k * DD + t];
    double s = waveReduceD((double)c * (double)c);
    int lane = t & 63, wid = t >> 6;
    if (lane == 0) lred[wid] = s;
    __syncthreads();
    if (t == 0) {
        double tot = lred[0] + lred[1] + lred[2] + lred[3];
        float nf = sqrtf((float)tot);
        mh = fmaxf(nf, 1e-12f);
    }
    __syncthreads();
    float wv = c / mh;
    w[k * DD + t] = wv;
    __syncthreads();
    double s2 = waveReduceD((double)wv * (double)wv);
    if (lane == 0) lred[wid] = s2;
    __syncthreads();
    if (t == 0) wsq[k] = (float)(lred[0] + lred[1] + lred[2] + lred[3]);
}

// one block per point: zsq[n] = sum_d z[n,d]^2  (z is NCHW)
__global__ __launch_bounds__(256) void zsq_kernel(
    const float* __restrict__ z, float* __restrict__ zsq) {
    __shared__ double lred[4];
    int n = blockIdx.x, t = threadIdx.x;
    int b = n >> 10, hw = n & 1023;
    float v = z[(b * DD + t) * 1024 + hw];
    double s = waveReduceD((double)v * (double)v);
    int lane = t & 63, wid = t >> 6;
    if (lane == 0) lred[wid] = s;
    __syncthreads();
    if (t == 0) zsq[n] = (float)(lred[0] + lred[1] + lred[2] + lred[3]);
}

// tiled fp32 GEMM + running argmin.  grid (128 n-tiles, KSPLIT), 256 threads.
// tile: 64 n-rows x 64 k-cols, 4x4 register micro-tile, D chunked by 16.
__global__ __launch_bounds__(256) void gemm_argmin(
    const float* __restrict__ z, const float* __restrict__ w,
    const float* __restrict__ wsq, const float* __restrict__ zsq,
    float* __restrict__ pval, int* __restrict__ pidx) {
    __shared__ float zt[16 * 68];
    __shared__ float wt[16 * 68];
    __shared__ float redv[64 * 16];
    __shared__ int redk[64 * 16];

    int t = threadIdx.x;
    int n0 = blockIdx.x * 64;
    int kbase = blockIdx.y * (KC / KSPLIT);
    int b = n0 >> 10, hw0 = n0 & 1023;
    int ti = t & 15, tj = t >> 4;

    float bestv[4];
    int bestk[4];
#pragma unroll
    for (int i = 0; i < 4; ++i) { bestv[i] = 3.4e38f; bestk[i] = 0; }
    float zsqr[4];
#pragma unroll
    for (int i = 0; i < 4; ++i) zsqr[i] = zsq[n0 + ti * 4 + i];

    for (int kt = 0; kt < (KC / KSPLIT) / 64; ++kt) {
        int k0 = kbase + kt * 64;
        float acc[4][4];
#pragma unroll
        for (int i = 0; i < 4; ++i)
#pragma unroll
            for (int j = 0; j < 4; ++j) acc[i][j] = 0.0f;

        for (int dc = 0; dc < 16; ++dc) {
            int d0 = dc * 16;
            // stage z tile [16 d][64 hw] — coalesced (hw contiguous in NCHW)
            {
                int hwl = t & 63, dl0 = t >> 6;
                const float* zp = z + (b * DD + d0 + dl0) * 1024 + hw0 + hwl;
#pragma unroll
                for (int j = 0; j < 4; ++j)
                    zt[(dl0 + j * 4) * 68 + hwl] = zp[j * 4 * 1024];
            }
            // stage w tile [16 d][64 k] via float4 row chunks
            {
                int kl = t >> 2, dd = (t & 3) * 4;
                const float4 wv = *(const float4*)&w[(k0 + kl) * DD + d0 + dd];
                wt[(dd + 0) * 68 + kl] = wv.x;
                wt[(dd + 1) * 68 + kl] = wv.y;
                wt[(dd + 2) * 68 + kl] = wv.z;
                wt[(dd + 3) * 68 + kl] = wv.w;
            }
            __syncthreads();
#pragma unroll
            for (int dl = 0; dl < 16; ++dl) {
                float4 za = *(const float4*)&zt[dl * 68 + ti * 4];
                float4 wb = *(const float4*)&wt[dl * 68 + tj * 4];
                float a0 = za.x, a1 = za.y, a2 = za.z, a3 = za.w;
                float b0 = wb.x, b1 = wb.y, b2 = wb.z, b3 = wb.w;
                acc[0][0] += a0 * b0; acc[0][1] += a0 * b1; acc[0][2] += a0 * b2; acc[0][3] += a0 * b3;
                acc[1][0] += a1 * b0; acc[1][1] += a1 * b1; acc[1][2] += a1 * b2; acc[1][3] += a1 * b3;
                acc[2][0] += a2 * b0; acc[2][1] += a2 * b1; acc[2][2] += a2 * b2; acc[2][3] += a2 * b3;
                acc[3][0] += a3 * b0; acc[3][1] += a3 * b1; acc[3][2] += a3 * b2; acc[3][3] += a3 * b3;
            }
            __syncthreads();
        }
        // epilogue: d = fl(fl(zsq+wsq) - fl(2*dot)); running min, ties -> lower k
#pragma unroll
        for (int j = 0; j < 4; ++j) {
            int kk = k0 + tj * 4 + j;
            float wq = wsq[kk];
#pragma unroll
            for (int i = 0; i < 4; ++i) {
                float t1 = zsqr[i] + wq;
                float dv = t1 - 2.0f * acc[i][j];
                if (dv < bestv[i]) { bestv[i] = dv; bestk[i] = kk; }
            }
        }
    }
    // cross-thread (tj) reduction per row
#pragma unroll
    for (int i = 0; i < 4; ++i) {
        redv[(ti * 4 + i) * 16 + tj] = bestv[i];
        redk[(ti * 4 + i) * 16 + tj] = bestk[i];
    }
    __syncthreads();
    if (t < 64) {
        float bv = 3.4e38f;
        int bk = 0x7fffffff;
#pragma unroll
        for (int s = 0; s < 16; ++s) {
            float v = redv[t * 16 + s];
            int k = redk[t * 16 + s];
            if (v < bv || (v == bv && k < bk)) { bv = v; bk = k; }
        }
        pval[blockIdx.y * NP + n0 + t] = bv;
        pidx[blockIdx.y * NP + n0 + t] = bk;
    }
}

// reduce over KSPLIT partials; write idx (int + float), histogram
__global__ __launch_bounds__(256) void reduce_idx(
    const float* __restrict__ pval, const int* __restrict__ pidx,
    int* __restrict__ idxw, float* __restrict__ idxout, int* __restrict__ hist) {
    int n = blockIdx.x * 256 + threadIdx.x;
    float bv = 3.4e38f;
    int bk = 0;
#pragma unroll
    for (int s = 0; s < KSPLIT; ++s) {
        float v = pval[s * NP + n];
        int k = pidx[s * NP + n];
        if (v < bv) { bv = v; bk = k; }  // s ascending == k ascending, strict < keeps lowest
    }
    idxw[n] = bk;
    idxout[n] = (float)bk;
    atomicAdd(&hist[bk], 1);
}

// z_q gather (NCHW) + loss partial sum
__global__ __launch_bounds__(256) void gather_loss(
    const float* __restrict__ z, const float* __restrict__ w,
    const int* __restrict__ idxw, float* __restrict__ out, double* __restrict__ lossd) {
    __shared__ double lred[4];
    int e = blockIdx.x * 256 + threadIdx.x;
    int b = e >> 18, d = (e >> 10) & 255, hw = e & 1023;
    int n = (b << 10) + hw;
    int k = idxw[n];
    float wv = w[k * DD + d];
    out[e] = wv;
    float df = wv - z[e];
    float sq = df * df;
    double s = waveReduceD((double)sq);
    int lane = threadIdx.x & 63, wid = threadIdx.x >> 6;
    if (lane == 0) lred[wid] = s;
    __syncthreads();
    if (threadIdx.x == 0)
        atomicAdd(lossd, lred[0] + lred[1] + lred[2] + lred[3]);
}

// single block: perplexity from histogram + final loss
__global__ __launch_bounds__(256) void finalize_kernel(
    const int* __restrict__ hist, const double* __restrict__ lossd,
    float* __restrict__ out) {
    __shared__ double lred[4];
    int t = threadIdx.x;
    double s = 0.0;
    for (int i = t; i < KC; i += 256) {
        float p = (float)hist[i] * (1.0f / 8192.0f);
        float lg = logf(p + 1e-10f);
        s += (double)(p * lg);
    }
    s = waveReduceD(s);
    int lane = t & 63, wid = t >> 6;
    if (lane == 0) lred[wid] = s;
    __syncthreads();
    if (t == 0) {
        double tot = lred[0] + lred[1] + lred[2] + lred[3];
        float m = (float)(lossd[0] / (double)ZQ_ELEMS);
        out[ZQ_ELEMS + NP] = m + 0.25f * m;            // loss
        out[ZQ_ELEMS + NP + 1] = expf(-(float)tot);    // perplexity
    }
}

extern "C" void kernel_launch(void* const* d_in, const int* in_sizes, int n_in,
                              void* d_out, int out_size, void* d_ws, size_t ws_size,
                              hipStream_t stream) {
    const float* z = (const float*)d_in[0];
    const float* cb = (const float*)d_in[1];
    float* out = (float*)d_out;
    char* ws = (char*)d_ws;

    float* w = (float*)(ws + OFF_W);
    float* wsq = (float*)(ws + OFF_WSQ);
    float* zsq = (float*)(ws + OFF_ZSQ);
    float* pval = (float*)(ws + OFF_PVAL);
    int* pidx = (int*)(ws + OFF_PIDX);
    int* idxw = (int*)(ws + OFF_IDX);
    int* hist = (int*)(ws + OFF_HIST);
    double* lossd = (double*)(ws + OFF_LOSS);

    // zero histogram + loss accumulator (adjacent)
    hipMemsetAsync(ws + OFF_HIST, 0, 32768 + 8, stream);

    normalize_kernel<<<KC, 256, 0, stream>>>(cb, w, wsq);
    zsq_kernel<<<NP, 256, 0, stream>>>(z, zsq);
    gemm_argmin<<<dim3(NP / 64, KSPLIT), 256, 0, stream>>>(z, w, wsq, zsq, pval, pidx);
    reduce_idx<<<NP / 256, 256, 0, stream>>>(pval, pidx, idxw, out + ZQ_ELEMS, hist);
    gather_loss<<<ZQ_ELEMS / 256, 256, 0, stream>>>(z, w, idxw, out, lossd);
    finalize_kernel<<<1, 256, 0, stream>>>(hist, lossd, out);
}